// Round 6
// baseline (3567.086 us; speedup 1.0000x reference)
//
#include <hip/hip_runtime.h>
#include <stdint.h>

// FPS (farthest point sampling), faithful to the reference:
//   dist = max(dist, ||p - last||)  (running MAX, per tf.maximum quirk)
//   idx  = argmax(dist)             (first-index tie-break)
// B=16, N=65536, npoint=1024 -> 1023 sequential rounds per batch.
//
// Layout: 16 blocks per batch, 512 threads/block, 8 points/thread, all
// coords + dist register-resident. Cross-block per-step combine via ONE
// persistent slot per (batch, block) holding a step-tagged packed key:
//   key = (step+1)<<48 | fp32bits(val)<<16 | (0xFFFF ^ idx)
// -> u64 max = (max val, tie -> min idx) within a step; tag strictly
// increases so no ABA and stale keys never outrank fresh ones.
// Workspace use: B*KBLK*8 = 2 KB (safe for any ws_size).

#define B_      16
#define N_      65536
#define STEPS   1023       // npoint - 1
#define KBLK    16         // blocks per batch
#define THREADS 512
#define PPT     8          // points per thread = N_/KBLK/THREADS
#define PTS_PER_BLK (N_/KBLK)   // 4096

__global__ void zero_slots(unsigned long long* ws, int n) {
    int i = blockIdx.x * blockDim.x + threadIdx.x;
    if (i < n) ws[i] = 0ull;
}

__launch_bounds__(THREADS, 2)
__global__ void fps_kernel(const float* __restrict__ xyz,
                           float* __restrict__ out,
                           unsigned long long* __restrict__ slots) {
    #pragma clang fp contract(off)

    const int blk  = blockIdx.x;
    const int b    = blk >> 4;     // batch
    const int k    = blk & 15;     // sub-block within batch
    const int tid  = threadIdx.x;
    const int wid  = tid >> 6;
    const int lane = tid & 63;

    const float* bx = xyz + (size_t)b * (N_ * 3);
    const int pbase = k * PTS_PER_BLK + tid * PPT;

    // ---- one-time load of my 8 points (96B contiguous, 6x float4) ----
    float a[24];
    const float4* src = (const float4*)(bx + (size_t)pbase * 3);
    #pragma unroll
    for (int j = 0; j < 6; ++j) {
        float4 v = src[j];
        a[4*j+0] = v.x; a[4*j+1] = v.y; a[4*j+2] = v.z; a[4*j+3] = v.w;
    }
    float px[PPT], py[PPT], pz[PPT], dist[PPT];
    #pragma unroll
    for (int p = 0; p < PPT; ++p) {
        px[p] = a[3*p]; py[p] = a[3*p+1]; pz[p] = a[3*p+2];
        dist[p] = 0.0f;
    }

    // initial center = point 0 of this batch
    float cx = bx[0], cy = bx[1], cz = bx[2];

    float* bout = out + (size_t)b * (1024 * 3);
    if (k == 0 && tid == 0) { bout[0] = cx; bout[1] = cy; bout[2] = cz; }

    __shared__ float lval[THREADS / 64];
    __shared__ int   lidx[THREADS / 64];
    __shared__ int   winIdx;

    unsigned long long* batchSlots = slots + (size_t)b * KBLK;

    for (int s = 0; s < STEPS; ++s) {
        // ---- local update + local argmax (ascending index => first-max) ----
        float bv = -1.0f; int bp = 0;
        #pragma unroll
        for (int p = 0; p < PPT; ++p) {
            float dx = px[p] - cx, dy = py[p] - cy, dz = pz[p] - cz;
            float sq = dx*dx + dy*dy + dz*dz;   // no fma (contract off)
            float d  = sqrtf(sq);               // correctly-rounded
            float nd = fmaxf(dist[p], d);
            dist[p] = nd;
            if (nd > bv) { bv = nd; bp = p; }   // strict > keeps earliest idx
        }
        int gi = pbase + bp;

        // ---- wave reduce (val desc, idx asc on tie) ----
        #pragma unroll
        for (int m = 1; m < 64; m <<= 1) {
            float ov = __shfl_xor(bv, m);
            int   oi = __shfl_xor(gi, m);
            if (ov > bv || (ov == bv && oi < gi)) { bv = ov; gi = oi; }
        }
        if (lane == 0) { lval[wid] = bv; lidx[wid] = gi; }
        __syncthreads();   // B1

        if (wid == 0) {
            float v2 = (lane < THREADS/64) ? lval[lane] : -1.0f;
            int   i2 = (lane < THREADS/64) ? lidx[lane] : 0x7FFFFFFF;
            #pragma unroll
            for (int m = 1; m < THREADS/64; m <<= 1) {
                float ov = __shfl_xor(v2, m);
                int   oi = __shfl_xor(i2, m);
                if (ov > v2 || (ov == v2 && oi < i2)) { v2 = ov; i2 = oi; }
            }
            // lane 0 publishes this block's best as a step-tagged key.
            if (lane == 0) {
                unsigned long long key =
                    ((unsigned long long)(s + 1) << 48) |
                    ((unsigned long long)__float_as_uint(v2) << 16) |
                    (unsigned long long)(0xFFFFu ^ (unsigned)i2);
                __hip_atomic_store(&batchSlots[k], key,
                                   __ATOMIC_RELEASE, __HIP_MEMORY_SCOPE_AGENT);
            }
            // poll all 16 slots until every tag == s+1 (bounded guard)
            const unsigned long long want = (unsigned long long)(s + 1);
            unsigned long long myv = 0ull;
            const int slot = lane & 15;
            int guard = 0;
            for (;;) {
                myv = __hip_atomic_load(&batchSlots[slot],
                                        __ATOMIC_RELAXED, __HIP_MEMORY_SCOPE_AGENT);
                if (__all((myv >> 48) == want)) break;
                if (++guard > 100000) break;   // bounded: never hang
            }
            // max over 16 slots (lanes repeat with period 16); stale keys
            // (smaller step tag) can never outrank fresh ones.
            #pragma unroll
            for (int m = 1; m < 16; m <<= 1) {
                unsigned long long ov = __shfl_xor(myv, m);
                if (ov > myv) myv = ov;
            }
            if (lane == 0)
                winIdx = (int)(0xFFFFu ^ (unsigned)(myv & 0xFFFFull));
        }
        __syncthreads();   // B2

        const int wi = winIdx;
        const float* cp = bx + (size_t)wi * 3;  // read-only data: any cache ok
        cx = cp[0]; cy = cp[1]; cz = cp[2];

        if (k == 0 && tid == 0) {
            float* o = bout + (size_t)(s + 1) * 3;
            o[0] = cx; o[1] = cy; o[2] = cz;
        }
    }
}

extern "C" void kernel_launch(void* const* d_in, const int* in_sizes, int n_in,
                              void* d_out, int out_size, void* d_ws, size_t ws_size,
                              hipStream_t stream) {
    const float* xyz = (const float*)d_in[0];
    float* out = (float*)d_out;
    unsigned long long* slots = (unsigned long long*)d_ws;

    const int nslots = B_ * KBLK;   // 256 u64 = 2 KB
    zero_slots<<<1, 256, 0, stream>>>(slots, nslots);
    fps_kernel<<<B_ * KBLK, THREADS, 0, stream>>>(xyz, out, slots);
}